// Round 12
// baseline (151.012 us; speedup 1.0000x reference)
//
#include <hip/hip_runtime.h>

namespace {

typedef short    v4s __attribute__((ext_vector_type(4)));
typedef float    v4f __attribute__((ext_vector_type(4)));
typedef float    f4  __attribute__((ext_vector_type(4)));
typedef unsigned u2  __attribute__((ext_vector_type(2)));

constexpr int Tt = 512;
constexpr int Dd = 64;
constexpr float LN2 = 0.69314718055994530942f;

// RNE bf16 pack (bit-twiddle; off critical path)
__device__ __forceinline__ unsigned pk_bf16(float a, float b) {
  unsigned ua = __float_as_uint(a), ub = __float_as_uint(b);
  ua += 0x7fffu + ((ua >> 16) & 1u);
  ub += 0x7fffu + ((ub >> 16) & 1u);
  return (ua >> 16) | (ub & 0xffff0000u);
}
// 1-instruction truncation pack via v_perm_b32 (exact for 0.0/1.0 inputs)
__device__ __forceinline__ unsigned pktrunc(float lo, float hi) {
  return __builtin_amdgcn_perm(__float_as_uint(hi), __float_as_uint(lo), 0x07060302u);
}
__device__ __forceinline__ v4s mk4(unsigned lo, unsigned hi) {
  union { unsigned u[2]; v4s s; } z;
  z.u[0] = lo; z.u[1] = hi; return z.s;
}
__device__ __forceinline__ float bf_lo(unsigned u) { return __uint_as_float(u << 16); }
__device__ __forceinline__ float bf_hi(unsigned u) { return __uint_as_float(u & 0xffff0000u); }

__device__ __forceinline__ v4f mfma16(v4s a, v4s b, v4f c) {
  return __builtin_amdgcn_mfma_f32_16x16x16bf16_1k(a, b, c, 0, 0, 0);
}
__device__ __forceinline__ float fexp2(float x) {
#if __has_builtin(__builtin_amdgcn_exp2f)
  return __builtin_amdgcn_exp2f(x);
#else
  return exp2f(x);
#endif
}
__device__ __forceinline__ float rdlane(float v, int idx) {
  return __uint_as_float(__builtin_amdgcn_readlane(__float_as_uint(v), idx));
}

// E LDS index (u2 = 8B units) for (t_local in [0,64), x, wblk)
__device__ __forceinline__ int eidx(int tl, int x, int wblk) {
  return tl * 64 + x * 4 + (wblk ^ (x >> 2));
}

__global__ __launch_bounds__(64, 1) void fhmm_fwd(
    const float* __restrict__ seq,     // [B, T, D]
    const int*   __restrict__ lengths, // [B]
    const float* __restrict__ pw,      // [16,16]
    const float* __restrict__ px,      // [16,16]
    const float* __restrict__ py,      // [16,16,64]
    float*       __restrict__ out,     // [B]
    u2*          __restrict__ wsdif)   // [16*4*64] B-frag table (shared, 32 KB)
{
  const int b = blockIdx.x;
  const int l = threadIdx.x;
  const int g = l >> 4;
  const int x = l & 15;

  __shared__ u2    Elds[64 * 64];          // ONE chunk: 64 t × 256 s, bf16 pairs
  __shared__ float Mbuf[512];              // global-t max shifts (final msum only)
  __shared__ __align__(16) float MxT[64 * 20];  // per-chunk M transpose pad

  // ---------- init: write dif B-frag table to ws; per-state base ----------
  float bfull[16];
#pragma unroll
  for (int st = 0; st < 16; ++st) {
    float part = 0.f;
#pragma unroll
    for (int c = 0; c < 4; ++c) {
      f4 p = *(const f4*)(py + (st * 16 + x) * 64 + c * 16 + g * 4);
      float q0 = __log2f(1.f - p.x), q1 = __log2f(1.f - p.y),
            q2 = __log2f(1.f - p.z), q3 = __log2f(1.f - p.w);
      part += (q0 + q1) + (q2 + q3);
      u2 wv;
      wv.x = pk_bf16(__log2f(p.x) - q0, __log2f(p.y) - q1);
      wv.y = pk_bf16(__log2f(p.z) - q2, __log2f(p.w) - q3);
      wsdif[(st * 4 + c) * 64 + l] = wv;   // all blocks write identical bytes
    }
    part += __shfl_xor(part, 16, 64);
    part += __shfl_xor(part, 32, 64);
    bfull[st] = part;   // base[st*16 + x]
  }

  v4s pwB, pxB;
  {
    const int r0 = (4 * g) * 16 + x;
    pwB = mk4(pk_bf16(pw[r0], pw[r0 + 16]), pk_bf16(pw[r0 + 32], pw[r0 + 48]));
    pxB = mk4(pk_bf16(px[r0], px[r0 + 16]), pk_bf16(px[r0 + 32], px[r0 + 48]));
  }
  const float p0w0 = pw[4 * g + 0], p0w1 = pw[4 * g + 1],
              p0w2 = pw[4 * g + 2], p0w3 = pw[4 * g + 3];
  const float px0 = px[x];

  const int len = lengths[b];
  const int nch = (len + 63) >> 6;
  const float* yb = seq + (size_t)b * (Tt * Dd);

  float acc = 0.f;
  v4f al = {0.f, 0.f, 0.f, 0.f};
  const v4f z4 = {0.f, 0.f, 0.f, 0.f};

// ---- prefetch helpers (static indices only) ----
#define YALOAD(TB)                                                          \
    _Pragma("unroll")                                                       \
    for (int mt_ = 0; mt_ < 4; ++mt_)                                       \
      _Pragma("unroll")                                                     \
      for (int c_ = 0; c_ < 4; ++c_)                                        \
        yv[mt_ * 4 + c_] = *(const f4*)(yb +                                \
            (size_t)((TB) + mt_ * 16 + x) * 64 + c_ * 16 + g * 4);

#define BQLOAD(DST, QN)                                                     \
    _Pragma("unroll")                                                       \
    for (int j_ = 0; j_ < 4; ++j_)                                          \
      _Pragma("unroll")                                                     \
      for (int c_ = 0; c_ < 4; ++c_)                                        \
        DST[j_ * 4 + c_] = wsdif[(((QN) * 4 + j_) * 4 + c_) * 64 + l];

#define GEMM_Q(BUF, QI)                                                     \
    {                                                                       \
      const float b0 = bfull[4 * (QI) + 0], b1 = bfull[4 * (QI) + 1],       \
                  b2 = bfull[4 * (QI) + 2], b3 = bfull[4 * (QI) + 3];       \
      _Pragma("unroll")                                                     \
      for (int mt_ = 0; mt_ < 4; ++mt_) {                                   \
        v4f a0 = z4, a1 = z4, a2 = z4, a3 = z4;                             \
        _Pragma("unroll")                                                   \
        for (int c_ = 0; c_ < 4; ++c_) {                                    \
          a0 = mfma16(ya16[mt_][c_], mk4(BUF[c_].x,      BUF[c_].y),      a0); \
          a1 = mfma16(ya16[mt_][c_], mk4(BUF[4 + c_].x,  BUF[4 + c_].y),  a1); \
          a2 = mfma16(ya16[mt_][c_], mk4(BUF[8 + c_].x,  BUF[8 + c_].y),  a2); \
          a3 = mfma16(ya16[mt_][c_], mk4(BUF[12 + c_].x, BUF[12 + c_].y), a3); \
        }                                                                   \
        _Pragma("unroll")                                                   \
        for (int id_ = 0; id_ < 4; ++id_) {                                 \
          const float e0 = a0[id_] + b0, e1 = a1[id_] + b1,                 \
                      e2 = a2[id_] + b2, e3 = a3[id_] + b3;                 \
          u2 wv;                                                            \
          wv.x = pk_bf16(e0, e1);                                           \
          wv.y = pk_bf16(e2, e3);                                           \
          Elds[eidx(mt_ * 16 + 4 * g + id_, x, (QI))] = wv;                 \
          const float mq = fmaxf(fmaxf(e0, e1), fmaxf(e2, e3));             \
          mx[mt_][id_] = fmaxf(mx[mt_][id_], mq);                           \
        }                                                                   \
      }                                                                     \
    }

  f4 yv[16];        // next-chunk raw y (prefetched under the scan)
  u2 BqA[16], BqB[16];
  YALOAD(0)
  BQLOAD(BqA, 0)

#pragma unroll 1
  for (int ch = 0; ch < nch; ++ch) {
    const int tb = ch * 64;

    // ======== chunk GEMM: E'[t][s] = base[s] + sum_d y[t][d] dif[s][d] ========
    v4s ya16[4][4];
#pragma unroll
    for (int mt = 0; mt < 4; ++mt)
#pragma unroll
      for (int c = 0; c < 4; ++c)
        ya16[mt][c] = mk4(pktrunc(yv[mt * 4 + c].x, yv[mt * 4 + c].y),
                          pktrunc(yv[mt * 4 + c].z, yv[mt * 4 + c].w));
    float mx[4][4];
#pragma unroll
    for (int mt = 0; mt < 4; ++mt)
#pragma unroll
      for (int id = 0; id < 4; ++id) mx[mt][id] = -1e30f;

    BQLOAD(BqB, 1)          // q1 frags land under q0's 16 MFMAs
    GEMM_Q(BqA, 0)
    BQLOAD(BqA, 2)
    GEMM_Q(BqB, 1)
    BQLOAD(BqB, 3)
    GEMM_Q(BqA, 2)
    GEMM_Q(BqB, 3)

    // M'[t] = max_s E' via LDS transpose; lane l ends holding M[tb+l]
#pragma unroll
    for (int mt = 0; mt < 4; ++mt)
#pragma unroll
      for (int id = 0; id < 4; ++id)
        MxT[(mt * 16 + 4 * g + id) * 20 + x] = mx[mt][id];
    __syncthreads();
    float Mrow;
    {
      const f4* row = (const f4*)&MxT[l * 20];
      f4 r0 = row[0], r1 = row[1], r2 = row[2], r3 = row[3];
      const float m01 = fmaxf(fmaxf(r0.x, r0.y), fmaxf(r0.z, r0.w));
      const float m23 = fmaxf(fmaxf(r1.x, r1.y), fmaxf(r1.z, r1.w));
      const float m45 = fmaxf(fmaxf(r2.x, r2.y), fmaxf(r2.z, r2.w));
      const float m67 = fmaxf(fmaxf(r3.x, r3.y), fmaxf(r3.z, r3.w));
      Mrow = fmaxf(fmaxf(m01, m23), fmaxf(m45, m67));
      Mbuf[tb + l] = Mrow;      // kept for the final msum reduction
    }

    __syncthreads();   // GEMM + M writes -> scan reads

    // ---- issue next chunk's global prefetches; land under ~40k cyc of scan
    if (ch + 1 < nch) {
      YALOAD(tb + 64)
      BQLOAD(BqA, 0)
    }

    // ======== scan phase: steps t in [tb, te) ========
    const int te = (len < tb + 64) ? len : (tb + 64);
    int t = tb;
    u2 Ec = Elds[eidx(0, x, g)];

#define SCAN_STEP(TCUR, PF)                                                 \
    {                                                                       \
      u2 En_ = Ec;                                                          \
      PF                                                                    \
      const float Ms_ = rdlane(Mrow, (TCUR) & 63);                          \
      const float e0 = fexp2(bf_lo(Ec.x) - Ms_);                            \
      const float e1 = fexp2(bf_hi(Ec.x) - Ms_);                            \
      const float e2 = fexp2(bf_lo(Ec.y) - Ms_);                            \
      const float e3 = fexp2(bf_hi(Ec.y) - Ms_);                            \
      v4s a16 = mk4(pktrunc(al[0], al[1]), pktrunc(al[2], al[3]));          \
      v4f d1 = mfma16(a16, pwB, z4);                                        \
      v4s d16 = mk4(pktrunc(d1[0], d1[1]), pktrunc(d1[2], d1[3]));          \
      v4f d2 = mfma16(d16, pxB, z4);                                        \
      al[0] = d2[0] * e0; al[1] = d2[1] * e1;                               \
      al[2] = d2[2] * e2; al[3] = d2[3] * e3;                               \
      Ec = En_;                                                             \
    }

#define RENORM                                                              \
    {                                                                       \
      float S = (al[0] + al[1]) + (al[2] + al[3]);                          \
      _Pragma("unroll")                                                     \
      for (int o = 1; o <= 32; o <<= 1) S += __shfl_xor(S, o, 64);          \
      S = fmaxf(S, 1e-35f);                                                 \
      const float r = __builtin_amdgcn_rcpf(S);                             \
      al[0] *= r; al[1] *= r; al[2] *= r; al[3] *= r;                       \
      acc += __log2f(S);                                                    \
    }

    if (ch == 0) {   // peel t = 0: alpha0 = prior * e
      const float Ms_ = rdlane(Mrow, 0);
      const float e0 = fexp2(bf_lo(Ec.x) - Ms_);
      const float e1 = fexp2(bf_hi(Ec.x) - Ms_);
      const float e2 = fexp2(bf_lo(Ec.y) - Ms_);
      const float e3 = fexp2(bf_hi(Ec.y) - Ms_);
      al[0] = p0w0 * px0 * e0; al[1] = p0w1 * px0 * e1;
      al[2] = p0w2 * px0 * e2; al[3] = p0w3 * px0 * e3;
      t = 1;
      if (t < te) Ec = Elds[eidx(1, x, g)];
    }

    while (t < te && (t & 7)) {     // guarded entry until 8-aligned
      SCAN_STEP(t,
        if (t + 1 < te) { En_ = Elds[eidx((t + 1) & 63, x, g)]; })
      if ((t & 7) == 7) RENORM
      ++t;
    }

    // fast path: 8-step groups, depth-2 E prefetch, pipelined shfl renorm
    const int ng = (te - t) >> 3;
    if (ng > 0) {
      u2 E1 = Elds[eidx((t + 1) & 63, x, g)];
      float snap = 0.f, Sready = 1.0f, rdy = 1.0f;
#pragma unroll 1
      for (int gi = 0; gi < ng; ++gi) {
#pragma unroll
        for (int k = 0; k < 8; ++k) {
          u2 E2 = Elds[eidx((t + k + 2) & 63, x, g)];   // 2-deep prefetch
          const float Ms_ = rdlane(Mrow, (t + k) & 63);
          float e0 = fexp2(bf_lo(Ec.x) - Ms_);
          float e1 = fexp2(bf_hi(Ec.x) - Ms_);
          float e2 = fexp2(bf_lo(Ec.y) - Ms_);
          float e3 = fexp2(bf_hi(Ec.y) - Ms_);
          if (k == 0) {       // apply previous group's renorm (off chain)
            e0 *= rdy; e1 *= rdy; e2 *= rdy; e3 *= rdy;
            acc += __log2f(Sready);
          }
          v4s a16 = mk4(pktrunc(al[0], al[1]), pktrunc(al[2], al[3]));
          v4f d1 = mfma16(a16, pwB, z4);
          v4s d16 = mk4(pktrunc(d1[0], d1[1]), pktrunc(d1[2], d1[3]));
          v4f d2 = mfma16(d16, pxB, z4);
          al[0] = d2[0] * e0; al[1] = d2[1] * e1;
          al[2] = d2[2] * e2; al[3] = d2[3] * e3;
          if (k == 0) snap = (al[0] + al[1]) + (al[2] + al[3]);  // snapshot
          if (k >= 1 && k <= 6)                                   // 1 hop/step
            snap += __shfl_xor(snap, 1 << (k - 1), 64);
          if (k == 7) {                                           // ready
            Sready = fmaxf(snap, 1e-35f);
            rdy = __builtin_amdgcn_rcpf(Sready);
          }
          Ec = E1; E1 = E2;
        }
        t += 8;
      }
      acc += __log2f(Sready);     // flush pending renorm
      al[0] *= rdy; al[1] *= rdy; al[2] *= rdy; al[3] *= rdy;
    }

    while (t < te) {                // guarded tail (final chunk only)
      SCAN_STEP(t,
        if (t + 1 < te) { En_ = Elds[eidx((t + 1) & 63, x, g)]; })
      if ((t & 7) == 7) RENORM
      ++t;
    }
#undef SCAN_STEP
#undef RENORM

    __syncthreads();   // scan reads done -> next chunk GEMM may overwrite
  }

  // ---------- finalize ----------
  float S = (al[0] + al[1]) + (al[2] + al[3]);
#pragma unroll
  for (int o = 1; o <= 32; o <<= 1) S += __shfl_xor(S, o, 64);
  S = fmaxf(S, 1e-35f);
  acc += __log2f(S);

  float msum = 0.f;
  for (int t2 = l; t2 < len; t2 += 64) msum += Mbuf[t2];
#pragma unroll
  for (int o = 1; o <= 32; o <<= 1) msum += __shfl_xor(msum, o, 64);

  if (l == 0) out[b] = LN2 * (acc + msum);
}

} // namespace

extern "C" void kernel_launch(void* const* d_in, const int* in_sizes, int n_in,
                              void* d_out, int out_size, void* d_ws, size_t ws_size,
                              hipStream_t stream) {
  const float* seq     = (const float*)d_in[0];
  const int*   lengths = (const int*)d_in[1];
  const float* pw      = (const float*)d_in[2];
  const float* px      = (const float*)d_in[3];
  const float* py      = (const float*)d_in[4];
  float*       out     = (float*)d_out;
  u2*          wsdif   = (u2*)d_ws;    // 32 KB shared B-frag table

  hipLaunchKernelGGL(fhmm_fwd, dim3(1024), dim3(64), 0, stream,
                     seq, lengths, pw, px, py, out, wsdif);
}

// Round 13
// 139.780 us; speedup vs baseline: 1.0804x; 1.0804x over previous
//
#include <hip/hip_runtime.h>

namespace {

typedef short    v4s __attribute__((ext_vector_type(4)));
typedef float    v4f __attribute__((ext_vector_type(4)));
typedef float    f4  __attribute__((ext_vector_type(4)));
typedef unsigned u2  __attribute__((ext_vector_type(2)));

constexpr int Tt = 512;
constexpr int Dd = 64;
constexpr float LN2 = 0.69314718055994530942f;

// RNE bf16 pack (bit-twiddle; off critical path)
__device__ __forceinline__ unsigned pk_bf16(float a, float b) {
  unsigned ua = __float_as_uint(a), ub = __float_as_uint(b);
  ua += 0x7fffu + ((ua >> 16) & 1u);
  ub += 0x7fffu + ((ub >> 16) & 1u);
  return (ua >> 16) | (ub & 0xffff0000u);
}
// 1-instruction truncation pack via v_perm_b32 (exact for 0/1; ok for alpha)
__device__ __forceinline__ unsigned pktrunc(float lo, float hi) {
  return __builtin_amdgcn_perm(__float_as_uint(hi), __float_as_uint(lo), 0x07060302u);
}
__device__ __forceinline__ v4s mk4(unsigned lo, unsigned hi) {
  union { unsigned u[2]; v4s s; } z;
  z.u[0] = lo; z.u[1] = hi; return z.s;
}
__device__ __forceinline__ float bf_lo(unsigned u) { return __uint_as_float(u << 16); }
__device__ __forceinline__ float bf_hi(unsigned u) { return __uint_as_float(u & 0xffff0000u); }

__device__ __forceinline__ v4f mfma16(v4s a, v4s b, v4f c) {
  return __builtin_amdgcn_mfma_f32_16x16x16bf16_1k(a, b, c, 0, 0, 0);
}
__device__ __forceinline__ float fexp2(float x) {
#if __has_builtin(__builtin_amdgcn_exp2f)
  return __builtin_amdgcn_exp2f(x);
#else
  return exp2f(x);
#endif
}
__device__ __forceinline__ float rdlane(float v, int idx) {
  return __uint_as_float(__builtin_amdgcn_readlane(__float_as_uint(v), idx));
}

// E LDS index (u2 = 8B units) for (t_local in [0,32), x, wblk)
__device__ __forceinline__ int eidx(int tl, int x, int wblk) {
  return tl * 64 + x * 4 + (wblk ^ (x >> 2));
}

__global__ __launch_bounds__(64, 1) void fhmm_seg(
    const float* __restrict__ seq,     // [B, T, D]
    const int*   __restrict__ lengths, // [B]
    const float* __restrict__ pw,      // [16,16]
    const float* __restrict__ px,      // [16,16]
    const float* __restrict__ py,      // [16,16,64]
    float*       __restrict__ part,    // [2B] per-segment partials (log2 units)
    u2*          __restrict__ wsdif)   // [16*4*64] B-frag table (shared, 32 KB)
{
  const int bid = blockIdx.x;
  const int b = bid >> 1;
  const int p = bid & 1;
  const int l = threadIdx.x;
  const int g = l >> 4;
  const int x = l & 15;

  const int len = lengths[b];
  int mid = ((len + 32) >> 1) & ~31;   // chunk-aligned split point
  if (mid < 32) mid = 32;
  const bool split = (mid < len);

  if (p == 1 && !split) {              // short sequence: p0 does everything
    if (l == 0) part[bid] = 0.f;
    return;
  }

  __shared__ u2    Elds[32 * 64];      // ONE 32-step chunk: 32 t × 256 s bf16
  __shared__ float Mbuf[288];          // this block's max shifts (local index)
  __shared__ __align__(16) float MxT[32 * 20];  // M transpose pad

  // ---------- init: write dif B-frag table to ws; per-state base ----------
  float bfull[16];
#pragma unroll
  for (int st = 0; st < 16; ++st) {
    float pt = 0.f;
#pragma unroll
    for (int c = 0; c < 4; ++c) {
      f4 pv = *(const f4*)(py + (st * 16 + x) * 64 + c * 16 + g * 4);
      float q0 = __log2f(1.f - pv.x), q1 = __log2f(1.f - pv.y),
            q2 = __log2f(1.f - pv.z), q3 = __log2f(1.f - pv.w);
      pt += (q0 + q1) + (q2 + q3);
      u2 wv;
      wv.x = pk_bf16(__log2f(pv.x) - q0, __log2f(pv.y) - q1);
      wv.y = pk_bf16(__log2f(pv.z) - q2, __log2f(pv.w) - q3);
      wsdif[(st * 4 + c) * 64 + l] = wv;   // all blocks write identical bytes
    }
    pt += __shfl_xor(pt, 16, 64);
    pt += __shfl_xor(pt, 32, 64);
    bfull[st] = pt;   // base[st*16 + x]
  }

  v4s pwB, pxB;
  {
    const int r0 = (4 * g) * 16 + x;
    pwB = mk4(pk_bf16(pw[r0], pw[r0 + 16]), pk_bf16(pw[r0 + 32], pw[r0 + 48]));
    pxB = mk4(pk_bf16(px[r0], px[r0 + 16]), pk_bf16(px[r0 + 32], px[r0 + 48]));
  }
  const float p0w0 = pw[4 * g + 0], p0w1 = pw[4 * g + 1],
              p0w2 = pw[4 * g + 2], p0w3 = pw[4 * g + 3];
  const float px0 = px[x];

  const int t_acc  = p ? mid : 0;                       // first accounted step
  const int t_stop = p ? len : (split ? mid : len);     // one-past-last step
  const int c_lo   = p ? ((mid - 32) >> 5) : 0;
  const int c_hi   = (t_stop + 31) >> 5;
  const int mbase  = c_lo * 32;

  const float* yb = seq + (size_t)b * (Tt * Dd);

  float acc = 0.f;                      // log2 of accounted renorm factors
  v4f al;                               // alpha (w=4g+id regs, x lanes)
  al[0] = al[1] = al[2] = al[3] = (p ? 1.f : 0.f);   // p1: uniform warmup init
  const v4f z4 = {0.f, 0.f, 0.f, 0.f};

#pragma unroll 1
  for (int ch = c_lo; ch < c_hi; ++ch) {
    const int tb = ch * 32;
    const float accf = (tb >= t_acc) ? 1.0f : 0.0f;   // warmup chunk: 0

    // ======== chunk GEMM: E'[t][s] = base[s] + sum_d y[t][d] dif[s][d] ======
    v4s ya16[2][4];
#pragma unroll
    for (int mt = 0; mt < 2; ++mt) {
      const float* yp = yb + (size_t)(tb + mt * 16 + x) * 64 + g * 4;
      f4 y0 = *(const f4*)(yp + 0);
      f4 y1 = *(const f4*)(yp + 16);
      f4 y2 = *(const f4*)(yp + 32);
      f4 y3 = *(const f4*)(yp + 48);
      ya16[mt][0] = mk4(pktrunc(y0.x, y0.y), pktrunc(y0.z, y0.w));
      ya16[mt][1] = mk4(pktrunc(y1.x, y1.y), pktrunc(y1.z, y1.w));
      ya16[mt][2] = mk4(pktrunc(y2.x, y2.y), pktrunc(y2.z, y2.w));
      ya16[mt][3] = mk4(pktrunc(y3.x, y3.y), pktrunc(y3.z, y3.w));
    }
    float mx[2][4];
#pragma unroll
    for (int mt = 0; mt < 2; ++mt)
#pragma unroll
      for (int id = 0; id < 4; ++id) mx[mt][id] = -1e30f;

#pragma unroll
    for (int q = 0; q < 4; ++q) {
      u2 Bq[4][4];
#pragma unroll
      for (int j = 0; j < 4; ++j)
#pragma unroll
        for (int c = 0; c < 4; ++c)
          Bq[j][c] = wsdif[(((q * 4 + j) * 4 + c)) * 64 + l];
      const float b0 = bfull[4 * q + 0], b1 = bfull[4 * q + 1],
                  b2 = bfull[4 * q + 2], b3 = bfull[4 * q + 3];
#pragma unroll
      for (int mt = 0; mt < 2; ++mt) {
        v4f a0 = z4, a1 = z4, a2 = z4, a3 = z4;
#pragma unroll
        for (int c = 0; c < 4; ++c) {
          a0 = mfma16(ya16[mt][c], mk4(Bq[0][c].x, Bq[0][c].y), a0);
          a1 = mfma16(ya16[mt][c], mk4(Bq[1][c].x, Bq[1][c].y), a1);
          a2 = mfma16(ya16[mt][c], mk4(Bq[2][c].x, Bq[2][c].y), a2);
          a3 = mfma16(ya16[mt][c], mk4(Bq[3][c].x, Bq[3][c].y), a3);
        }
#pragma unroll
        for (int id = 0; id < 4; ++id) {
          const float e0 = a0[id] + b0, e1 = a1[id] + b1,
                      e2 = a2[id] + b2, e3 = a3[id] + b3;
          u2 wv;
          wv.x = pk_bf16(e0, e1);
          wv.y = pk_bf16(e2, e3);
          Elds[eidx(mt * 16 + 4 * g + id, x, q)] = wv;
          const float mq = fmaxf(fmaxf(e0, e1), fmaxf(e2, e3));
          mx[mt][id] = fmaxf(mx[mt][id], mq);
        }
      }
    }
    // M'[t] = max_s E' via LDS transpose; lane l holds M[tb + (l&31)]
#pragma unroll
    for (int mt = 0; mt < 2; ++mt)
#pragma unroll
      for (int id = 0; id < 4; ++id)
        MxT[(mt * 16 + 4 * g + id) * 20 + x] = mx[mt][id];
    __syncthreads();
    float Mrow;
    {
      const f4* row = (const f4*)&MxT[(l & 31) * 20];
      f4 r0 = row[0], r1 = row[1], r2 = row[2], r3 = row[3];
      const float m01 = fmaxf(fmaxf(r0.x, r0.y), fmaxf(r0.z, r0.w));
      const float m23 = fmaxf(fmaxf(r1.x, r1.y), fmaxf(r1.z, r1.w));
      const float m45 = fmaxf(fmaxf(r2.x, r2.y), fmaxf(r2.z, r2.w));
      const float m67 = fmaxf(fmaxf(r3.x, r3.y), fmaxf(r3.z, r3.w));
      Mrow = fmaxf(fmaxf(m01, m23), fmaxf(m45, m67));
    }
    if (l < 32) Mbuf[tb - mbase + l] = Mrow;

    // ======== scan phase: steps t in [tb, te) ========
    const int te = (t_stop < tb + 32) ? t_stop : (tb + 32);
    int t = tb;
    u2 Ec = Elds[eidx(0, x, g)];

#define SCAN_STEP(TCUR, PF)                                                 \
    {                                                                       \
      u2 En_ = Ec;                                                          \
      PF                                                                    \
      const float Ms_ = rdlane(Mrow, (TCUR) & 31);                          \
      const float e0 = fexp2(bf_lo(Ec.x) - Ms_);                            \
      const float e1 = fexp2(bf_hi(Ec.x) - Ms_);                            \
      const float e2 = fexp2(bf_lo(Ec.y) - Ms_);                            \
      const float e3 = fexp2(bf_hi(Ec.y) - Ms_);                            \
      v4s a16 = mk4(pktrunc(al[0], al[1]), pktrunc(al[2], al[3]));          \
      v4f d1 = mfma16(a16, pwB, z4);                                        \
      v4s d16 = mk4(pktrunc(d1[0], d1[1]), pktrunc(d1[2], d1[3]));          \
      v4f d2 = mfma16(d16, pxB, z4);                                        \
      al[0] = d2[0] * e0; al[1] = d2[1] * e1;                               \
      al[2] = d2[2] * e2; al[3] = d2[3] * e3;                               \
      Ec = En_;                                                             \
    }

#define RENORM                                                              \
    {                                                                       \
      float S = (al[0] + al[1]) + (al[2] + al[3]);                          \
      _Pragma("unroll")                                                     \
      for (int o = 1; o <= 32; o <<= 1) S += __shfl_xor(S, o, 64);          \
      S = fmaxf(S, 1e-35f);                                                 \
      const float r = __builtin_amdgcn_rcpf(S);                             \
      al[0] *= r; al[1] *= r; al[2] *= r; al[3] *= r;                       \
      acc += accf * __log2f(S);                                             \
    }

    if (p == 0 && ch == 0) {   // peel t = 0: alpha0 = prior * e
      const float Ms_ = rdlane(Mrow, 0);
      const float e0 = fexp2(bf_lo(Ec.x) - Ms_);
      const float e1 = fexp2(bf_hi(Ec.x) - Ms_);
      const float e2 = fexp2(bf_lo(Ec.y) - Ms_);
      const float e3 = fexp2(bf_hi(Ec.y) - Ms_);
      al[0] = p0w0 * px0 * e0; al[1] = p0w1 * px0 * e1;
      al[2] = p0w2 * px0 * e2; al[3] = p0w3 * px0 * e3;
      t = 1;
      if (t < te) Ec = Elds[eidx(1, x, g)];
    }

    while (t < te && (t & 7)) {     // guarded entry until 8-aligned
      SCAN_STEP(t,
        if (t + 1 < te) { En_ = Elds[eidx((t + 1) & 31, x, g)]; })
      if ((t & 7) == 7) RENORM
      ++t;
    }

    // fast path: 8-step groups, depth-2 E prefetch, pipelined shfl renorm
    const int ng = (te - t) >> 3;
    if (ng > 0) {
      u2 E1 = Elds[eidx((t + 1) & 31, x, g)];
      float snap = 0.f, Sready = 1.0f, rdy = 1.0f;
#pragma unroll 1
      for (int gi = 0; gi < ng; ++gi) {
#pragma unroll
        for (int k = 0; k < 8; ++k) {
          u2 E2 = Elds[eidx((t + k + 2) & 31, x, g)];   // 2-deep prefetch
          const float Ms_ = rdlane(Mrow, (t + k) & 31);
          float e0 = fexp2(bf_lo(Ec.x) - Ms_);
          float e1 = fexp2(bf_hi(Ec.x) - Ms_);
          float e2 = fexp2(bf_lo(Ec.y) - Ms_);
          float e3 = fexp2(bf_hi(Ec.y) - Ms_);
          if (k == 0) {       // apply previous group's renorm (off chain)
            e0 *= rdy; e1 *= rdy; e2 *= rdy; e3 *= rdy;
            acc += accf * __log2f(Sready);
          }
          v4s a16 = mk4(pktrunc(al[0], al[1]), pktrunc(al[2], al[3]));
          v4f d1 = mfma16(a16, pwB, z4);
          v4s d16 = mk4(pktrunc(d1[0], d1[1]), pktrunc(d1[2], d1[3]));
          v4f d2 = mfma16(d16, pxB, z4);
          al[0] = d2[0] * e0; al[1] = d2[1] * e1;
          al[2] = d2[2] * e2; al[3] = d2[3] * e3;
          if (k == 0) snap = (al[0] + al[1]) + (al[2] + al[3]);  // snapshot
          if (k >= 1 && k <= 6)                                   // 1 hop/step
            snap += __shfl_xor(snap, 1 << (k - 1), 64);
          if (k == 7) {                                           // ready
            Sready = fmaxf(snap, 1e-35f);
            rdy = __builtin_amdgcn_rcpf(Sready);
          }
          Ec = E1; E1 = E2;
        }
        t += 8;
      }
      acc += accf * __log2f(Sready);     // flush pending renorm
      al[0] *= rdy; al[1] *= rdy; al[2] *= rdy; al[3] *= rdy;
    }

    while (t < te) {                // guarded tail (final chunk only)
      SCAN_STEP(t,
        if (t + 1 < te) { En_ = Elds[eidx((t + 1) & 31, x, g)]; })
      if ((t & 7) == 7) RENORM
      ++t;
    }
#undef SCAN_STEP
#undef RENORM

    __syncthreads();   // scan reads done -> next chunk GEMM may overwrite
  }

  // ---------- finalize: fold final mass (always accounted) + msum ----------
  float S = (al[0] + al[1]) + (al[2] + al[3]);
#pragma unroll
  for (int o = 1; o <= 32; o <<= 1) S += __shfl_xor(S, o, 64);
  S = fmaxf(S, 1e-35f);
  acc += __log2f(S);

  float msum = 0.f;
  for (int t2 = t_acc + l; t2 < t_stop; t2 += 64) msum += Mbuf[t2 - mbase];
#pragma unroll
  for (int o = 1; o <= 32; o <<= 1) msum += __shfl_xor(msum, o, 64);

  if (l == 0) part[bid] = acc + msum;
}

__global__ void fhmm_reduce(const float* __restrict__ part,
                            float* __restrict__ out) {
  const int i = blockIdx.x * 256 + threadIdx.x;   // 4 blocks x 256 = 1024
  out[i] = LN2 * (part[2 * i] + part[2 * i + 1]);
}

} // namespace

extern "C" void kernel_launch(void* const* d_in, const int* in_sizes, int n_in,
                              void* d_out, int out_size, void* d_ws, size_t ws_size,
                              hipStream_t stream) {
  const float* seq     = (const float*)d_in[0];
  const int*   lengths = (const int*)d_in[1];
  const float* pw      = (const float*)d_in[2];
  const float* px      = (const float*)d_in[3];
  const float* py      = (const float*)d_in[4];
  float*       out     = (float*)d_out;
  u2*          wsdif   = (u2*)d_ws;                         // 32 KB table
  float*       part    = (float*)((char*)d_ws + 32768);     // 8 KB partials

  hipLaunchKernelGGL(fhmm_seg, dim3(2048), dim3(64), 0, stream,
                     seq, lengths, pw, px, py, part, wsdif);
  hipLaunchKernelGGL(fhmm_reduce, dim3(4), dim3(256), 0, stream, part, out);
}